// Round 2
// baseline (1658.012 us; speedup 1.0000x reference)
//
#include <hip/hip_runtime.h>
#include <hip/hip_bf16.h>

#define B_    8
#define C_    192
#define H_    128
#define W_    128
#define HW_   16384
#define HEADS 4
#define S_    48
#define EPS_  1e-5f

typedef __hip_bfloat16 bf16;

__device__ inline float ld(const bf16* p)  { return __bfloat162float(*p); }
__device__ inline void  st(float* p, float v) { *p = v; }
__device__ inline void  st(bf16* p, float v)  { *p = __float2bfloat16(v); }

// ---------------------------------------------------------------------------
__global__ __launch_bounds__(256) void zero_kernel(float* p, int n) {
  int i = blockIdx.x * 256 + threadIdx.x;
  if (i < n) p[i] = 0.f;
}

// ---------------------------------------------------------------------------
// LayerNorm over channel axis per spatial position. x:[B][C][HW] fp32 -> bf16
// ---------------------------------------------------------------------------
__global__ __launch_bounds__(256) void ln_kernel(
    const float* __restrict__ x, const float* __restrict__ lw,
    const float* __restrict__ lb, bf16* __restrict__ xn) {
  int p = blockIdx.x * 256 + threadIdx.x;           // 0 .. B*HW
  if (p >= B_ * HW_) return;
  int b = p >> 14, pos = p & (HW_ - 1);
  const float* xp = x + (size_t)b * C_ * HW_ + pos;
  float sum = 0.f, sumsq = 0.f;
  for (int c = 0; c < C_; c++) {
    float v = xp[(size_t)c * HW_];
    sum += v; sumsq += v * v;
  }
  float mu = sum * (1.0f / C_);
  float var = sumsq * (1.0f / C_) - mu * mu;
  float rstd = rsqrtf(var + EPS_);
  bf16* op = xn + (size_t)b * C_ * HW_ + pos;
  for (int c = 0; c < C_; c++) {
    float v = xp[(size_t)c * HW_];
    st(op + (size_t)c * HW_, (v - mu) * rstd * lw[c] + lb[c]);
  }
}

// ---------------------------------------------------------------------------
// Pointwise conv = GEMM: out[b,o,p] = sum_c wt[o,c]*in[b,c,p] + bias[o] (+res)
// Tile: 32 outputs x 128 positions, K-chunk 32. Block 256 threads, 4x4 micro.
// ---------------------------------------------------------------------------
template <bool RES, typename OutT>
__global__ __launch_bounds__(256) void pw_gemm_kernel(
    const bf16* __restrict__ in, const float* __restrict__ wt,
    const float* __restrict__ bias, const bf16* __restrict__ residual,
    OutT* __restrict__ out) {
  __shared__ float sIn[32][128];
  __shared__ float sW[32][33];
  int tid = threadIdx.x;
  int posBase = blockIdx.x * 128;
  int oBase = blockIdx.y * 32;
  int b = blockIdx.z;
  const bf16* inb = in + (size_t)b * C_ * HW_;
  int tx = tid & 31;   // position group
  int ty = tid >> 5;   // output-channel group (0..7)
  float acc[4][4] = {};
  for (int k0 = 0; k0 < C_; k0 += 32) {
#pragma unroll
    for (int i = 0; i < 16; i++) {
      int idx = tid + i * 256;
      int r = idx >> 7, cpos = idx & 127;
      sIn[r][cpos] = ld(inb + (size_t)(k0 + r) * HW_ + posBase + cpos);
    }
#pragma unroll
    for (int i = 0; i < 4; i++) {
      int idx = tid + i * 256;
      int r = idx >> 5, cc = idx & 31;
      sW[r][cc] = wt[(oBase + r) * C_ + k0 + cc];
    }
    __syncthreads();
#pragma unroll 8
    for (int k = 0; k < 32; k++) {
      float bv[4];
#pragma unroll
      for (int i = 0; i < 4; i++) bv[i] = sIn[k][tx + 32 * i];
#pragma unroll
      for (int j = 0; j < 4; j++) {
        float av = sW[ty * 4 + j][k];
#pragma unroll
        for (int i = 0; i < 4; i++) acc[j][i] += av * bv[i];
      }
    }
    __syncthreads();
  }
#pragma unroll
  for (int j = 0; j < 4; j++) {
    int o = oBase + ty * 4 + j;
    float bs = bias[o];
#pragma unroll
    for (int i = 0; i < 4; i++) {
      int pos = posBase + tx + 32 * i;
      size_t off = ((size_t)b * C_ + o) * HW_ + pos;
      float v = acc[j][i] + bs;
      if (RES) v += ld(residual + off);
      st(out + off, v);
    }
  }
}

// ---------------------------------------------------------------------------
// Depthwise 3x3, SAME zero padding. w9:[C][9]
// ---------------------------------------------------------------------------
__global__ __launch_bounds__(256) void dw_kernel(
    const bf16* __restrict__ in, const float* __restrict__ w9,
    const float* __restrict__ bias, bf16* __restrict__ out) {
  int idx = blockIdx.x * 256 + threadIdx.x;
  if (idx >= B_ * C_ * HW_) return;
  int pos = idx & (HW_ - 1);
  int bc = idx >> 14;
  int c = bc % C_;
  int h = pos >> 7, w = pos & 127;
  const bf16* ip = in + (size_t)bc * HW_;
  const float* wp = w9 + c * 9;
  float acc = bias[c];
#pragma unroll
  for (int dy = 0; dy < 3; dy++) {
    int hh = h + dy - 1;
    if (hh < 0 || hh >= H_) continue;
#pragma unroll
    for (int dx = 0; dx < 3; dx++) {
      int ww = w + dx - 1;
      if (ww < 0 || ww >= W_) continue;
      acc += ld(ip + hh * W_ + ww) * wp[dy * 3 + dx];
    }
  }
  st(out + idx, acc);
}

// ---------------------------------------------------------------------------
// Gram: logits[b,hd,sk,sq] = sum_pos K[b,hd*S+sk,pos]*Q[b,hd*S+sq,pos]
// Block = (pos-chunk of 1024, bh). 16x16 thread grid, 3x3 micro, atomicAdd.
// ---------------------------------------------------------------------------
__global__ __launch_bounds__(256) void gram_kernel(
    const bf16* __restrict__ Q, const bf16* __restrict__ K,
    float* __restrict__ logits) {
  __shared__ float sK[S_][65];
  __shared__ float sQ[S_][65];
  int bh = blockIdx.y;
  int b = bh >> 2, hd = bh & 3;
  int p0base = blockIdx.x * (HW_ / 16);   // 1024-position chunk
  const bf16* Qb = Q + ((size_t)b * C_ + hd * S_) * HW_;
  const bf16* Kb = K + ((size_t)b * C_ + hd * S_) * HW_;
  int tid = threadIdx.x;
  int tx = tid & 15, ty = tid >> 4;
  float acc[3][3] = {};
  for (int t0 = 0; t0 < 1024; t0 += 64) {
    int p0 = p0base + t0;
#pragma unroll
    for (int i = 0; i < 12; i++) {
      int idx = tid + i * 256;
      int r = idx >> 6, cc = idx & 63;
      sK[r][cc] = ld(Kb + (size_t)r * HW_ + p0 + cc);
      sQ[r][cc] = ld(Qb + (size_t)r * HW_ + p0 + cc);
    }
    __syncthreads();
    for (int p = 0; p < 64; p++) {
      float kv[3], qv[3];
#pragma unroll
      for (int r = 0; r < 3; r++) kv[r] = sK[ty * 3 + r][p];
#pragma unroll
      for (int r = 0; r < 3; r++) qv[r] = sQ[tx * 3 + r][p];
#pragma unroll
      for (int r = 0; r < 3; r++)
#pragma unroll
        for (int q = 0; q < 3; q++) acc[r][q] += kv[r] * qv[q];
    }
    __syncthreads();
  }
  float* lp = logits + (size_t)bh * S_ * S_;
#pragma unroll
  for (int r = 0; r < 3; r++)
#pragma unroll
    for (int q = 0; q < 3; q++)
      atomicAdd(&lp[(ty * 3 + r) * S_ + (tx * 3 + q)], acc[r][q]);
}

// ---------------------------------------------------------------------------
// Softmax over last axis (sq), one thread per (b,hd,sk) row.
// ---------------------------------------------------------------------------
__global__ __launch_bounds__(256) void softmax_kernel(
    const float* __restrict__ logits, const float* __restrict__ alpha,
    float* __restrict__ att) {
  int row = blockIdx.x * 256 + threadIdx.x;   // 0..1535
  if (row >= B_ * HEADS * S_) return;
  float inv_a = 1.0f / alpha[0];
  const float* lp = logits + (size_t)row * S_;
  float v[S_];
  float m = -1e30f;
  for (int i = 0; i < S_; i++) {
    v[i] = lp[i] * inv_a;
    m = fmaxf(m, v[i]);
  }
  float s = 0.f;
  for (int i = 0; i < S_; i++) { v[i] = expf(v[i] - m); s += v[i]; }
  float inv_s = 1.0f / s;
  float* ap = att + (size_t)row * S_;
  for (int i = 0; i < S_; i++) ap[i] = v[i] * inv_s;
}

// ---------------------------------------------------------------------------
// out[b,hd*S+sq,pos] = sum_sk att[b,hd,sk,sq] * V[b,hd*S+sk,pos]
// Block = (128-pos chunk, bh). Each thread: one pos (x2 groups), 24 sq values.
// ---------------------------------------------------------------------------
__global__ __launch_bounds__(256) void av_kernel(
    const bf16* __restrict__ V, const float* __restrict__ att,
    bf16* __restrict__ out) {
  __shared__ float sV[S_][128];
  __shared__ float sA[S_][S_];
  int bh = blockIdx.y;
  int b = bh >> 2, hd = bh & 3;
  int p0 = blockIdx.x * 128;
  const bf16* Vb = V + ((size_t)b * C_ + hd * S_) * HW_;
  int tid = threadIdx.x;
  for (int i = tid; i < S_ * S_; i += 256)
    sA[i / S_][i % S_] = att[(size_t)bh * S_ * S_ + i];
#pragma unroll
  for (int i = 0; i < 24; i++) {
    int idx = tid + i * 256;
    int r = idx >> 7, cc = idx & 127;
    sV[r][cc] = ld(Vb + (size_t)r * HW_ + p0 + cc);
  }
  __syncthreads();
  int px = tid & 127, ty = tid >> 7;   // ty 0..1
  float acc[24];
#pragma unroll
  for (int j = 0; j < 24; j++) acc[j] = 0.f;
  for (int sk = 0; sk < S_; sk++) {
    float v = sV[sk][px];
#pragma unroll
    for (int j = 0; j < 24; j++) acc[j] += v * sA[sk][ty + 2 * j];
  }
  bf16* ob = out + ((size_t)b * C_ + hd * S_) * HW_;
#pragma unroll
  for (int j = 0; j < 24; j++)
    st(ob + (size_t)(ty + 2 * j) * HW_ + p0 + px, acc[j]);
}

// ---------------------------------------------------------------------------
// Spatial 128x128 transpose per (b,c): out[i*W+j] = in[j*W+i]
// (this realizes the reference's view/transpose(2,3)/reshape quirk, H==W)
// ---------------------------------------------------------------------------
__global__ __launch_bounds__(256) void transpose_kernel(
    const bf16* __restrict__ in, bf16* __restrict__ out) {
  __shared__ bf16 tile[32][33];
  int bc = blockIdx.z;
  const bf16* ip = in + (size_t)bc * HW_;
  bf16* op = out + (size_t)bc * HW_;
  int x0 = blockIdx.x * 32, y0 = blockIdx.y * 32;
  int tx = threadIdx.x, ty0 = threadIdx.y;
  for (int i = ty0; i < 32; i += 8)
    tile[i][tx] = ip[(y0 + i) * W_ + x0 + tx];
  __syncthreads();
  for (int i = ty0; i < 32; i += 8)
    op[(x0 + i) * W_ + y0 + tx] = tile[tx][i];
}

// ---------------------------------------------------------------------------
extern "C" void kernel_launch(void* const* d_in, const int* in_sizes, int n_in,
                              void* d_out, int out_size, void* d_ws, size_t ws_size,
                              hipStream_t stream) {
  const float* x      = (const float*)d_in[0];
  const float* ln_w   = (const float*)d_in[1];
  const float* ln_b   = (const float*)d_in[2];
  const float* q_pw_w = (const float*)d_in[3];
  const float* q_pw_b = (const float*)d_in[4];
  const float* q_dw_w = (const float*)d_in[5];
  const float* q_dw_b = (const float*)d_in[6];
  const float* k_pw_w = (const float*)d_in[7];
  const float* k_pw_b = (const float*)d_in[8];
  const float* k_dw_w = (const float*)d_in[9];
  const float* k_dw_b = (const float*)d_in[10];
  const float* v_pw_w = (const float*)d_in[11];
  const float* v_pw_b = (const float*)d_in[12];
  const float* v_dw_w = (const float*)d_in[13];
  const float* v_dw_b = (const float*)d_in[14];
  const float* f_w    = (const float*)d_in[15];
  const float* f_b    = (const float*)d_in[16];
  const float* alpha  = (const float*)d_in[17];
  float* out = (float*)d_out;

  // Workspace (bf16 intermediates): 3*N*2B + 2*73728*4B ~= 152 MB
  size_t N = (size_t)B_ * C_ * HW_;           // 25,165,824
  bf16* xn   = (bf16*)d_ws;                   // LayerNorm output (residual source)
  bf16* tmp  = xn + N;                        // pw outputs / transposed att-out
  bf16* A    = tmp + N;                       // Q, then V
  float* logits = (float*)(A + N);            // [32][48][48]
  float* att    = logits + (size_t)B_ * HEADS * S_ * S_;
  // d_out doubles as scratch: K (bf16) until gram, then att-out (bf16),
  // finally the fp32 result.
  bf16* Kb     = (bf16*)d_out;
  bf16* attout = (bf16*)d_out;

  int nlog = B_ * HEADS * S_ * S_;            // 73728 = 288*256
  zero_kernel<<<dim3(nlog / 256), 256, 0, stream>>>(logits, nlog);

  ln_kernel<<<dim3(B_ * HW_ / 256), 256, 0, stream>>>(x, ln_w, ln_b, xn);

  dim3 gG(HW_ / 128, C_ / 32, B_);
  int dwBlocks = (B_ * C_ * HW_) / 256;

  // Q
  pw_gemm_kernel<false, bf16><<<gG, 256, 0, stream>>>(xn, q_pw_w, q_pw_b, nullptr, tmp);
  dw_kernel<<<dwBlocks, 256, 0, stream>>>(tmp, q_dw_w, q_dw_b, A);
  // K -> d_out scratch
  pw_gemm_kernel<false, bf16><<<gG, 256, 0, stream>>>(xn, k_pw_w, k_pw_b, nullptr, tmp);
  dw_kernel<<<dwBlocks, 256, 0, stream>>>(tmp, k_dw_w, k_dw_b, Kb);
  // attention matrix
  gram_kernel<<<dim3(16, B_ * HEADS), 256, 0, stream>>>(A, Kb, logits);
  softmax_kernel<<<dim3(6), 256, 0, stream>>>(logits, alpha, att);
  // V
  pw_gemm_kernel<false, bf16><<<gG, 256, 0, stream>>>(xn, v_pw_w, v_pw_b, nullptr, tmp);
  dw_kernel<<<dwBlocks, 256, 0, stream>>>(tmp, v_dw_w, v_dw_b, A);
  // att-weighted V -> d_out scratch (K is dead)
  av_kernel<<<dim3(HW_ / 128, B_ * HEADS), 256, 0, stream>>>(A, att, attout);
  // spatial transpose -> tmp
  transpose_kernel<<<dim3(4, 4, B_ * C_), dim3(32, 8), 0, stream>>>(attout, tmp);
  // final projection + bias + residual(xn) -> d_out (fp32)
  pw_gemm_kernel<true, float><<<gG, 256, 0, stream>>>(tmp, f_w, f_b, xn, out);
}

// Round 3
// 942.231 us; speedup vs baseline: 1.7597x; 1.7597x over previous
//
#include <hip/hip_runtime.h>
#include <hip/hip_bf16.h>

#define B_    8
#define C_    192
#define H_    128
#define W_    128
#define HW_   16384
#define HEADS 4
#define S_    48
#define EPS_  1e-5f

typedef __hip_bfloat16 bf16;
typedef unsigned short u16;
typedef __attribute__((ext_vector_type(8))) short short8;
typedef __attribute__((ext_vector_type(4))) short short4v;
typedef __attribute__((ext_vector_type(4))) float f32x4;

__device__ inline float ld(const bf16* p)  { return __bfloat162float(*p); }
__device__ inline void  st(float* p, float v) { *p = v; }
__device__ inline void  st(bf16* p, float v)  { *p = __float2bfloat16(v); }

// ---------------------------------------------------------------------------
__global__ __launch_bounds__(256) void zero_kernel(float* p, int n) {
  int i = blockIdx.x * 256 + threadIdx.x;
  if (i < n) p[i] = 0.f;
}

// ---------------------------------------------------------------------------
// LayerNorm over channel axis per spatial position. x:[B][C][HW] fp32 -> bf16
// ---------------------------------------------------------------------------
__global__ __launch_bounds__(256) void ln_kernel(
    const float* __restrict__ x, const float* __restrict__ lw,
    const float* __restrict__ lb, bf16* __restrict__ xn) {
  int p = blockIdx.x * 256 + threadIdx.x;           // 0 .. B*HW
  if (p >= B_ * HW_) return;
  int b = p >> 14, pos = p & (HW_ - 1);
  const float* xp = x + (size_t)b * C_ * HW_ + pos;
  float sum = 0.f, sumsq = 0.f;
  for (int c = 0; c < C_; c++) {
    float v = xp[(size_t)c * HW_];
    sum += v; sumsq += v * v;
  }
  float mu = sum * (1.0f / C_);
  float var = sumsq * (1.0f / C_) - mu * mu;
  float rstd = rsqrtf(var + EPS_);
  bf16* op = xn + (size_t)b * C_ * HW_ + pos;
  for (int c = 0; c < C_; c++) {
    float v = xp[(size_t)c * HW_];
    st(op + (size_t)c * HW_, (v - mu) * rstd * lw[c] + lb[c]);
  }
}

// ---------------------------------------------------------------------------
// Pointwise conv via MFMA: out[b,o,p] = sum_c wt[o,c]*in[b,c,p] + bias[o](+res)
// Block: 4 waves, tile 64 o x 256 pos. K=192 in 6 chunks of 32.
// LDS: sW [64][200] bf16 (full K, staged once); sX [256 pos][36] bf16 per chunk
//   (transposed staging: scalar u16 global loads -> lane-p-stride-1
//    ds_write_b64, conflict-free; row stride 18 dwords -> banks 18k%32 distinct)
// A frag: ds_read_b128 (2-way, free). B frag: 2x ds_read_b64 (conflict-free).
// ---------------------------------------------------------------------------
#define SWR 200
#define SXR 36
template <bool RES, typename OutT>
__global__ __launch_bounds__(256) void pw_mfma_kernel(
    const bf16* __restrict__ in, const float* __restrict__ wt,
    const float* __restrict__ bias, const bf16* __restrict__ residual,
    OutT* __restrict__ out) {
  __shared__ __align__(16) u16 sW[64 * SWR];
  __shared__ __align__(16) u16 sX[256 * SXR];
  int tid = threadIdx.x;
  int posBase = blockIdx.x * 256;
  int oBase = blockIdx.y * 64;
  int b = blockIdx.z;
  int wv = tid >> 6, lane = tid & 63;
  int quad = lane >> 4, l15 = lane & 15;

  // ---- stage W (fp32 -> bf16), whole 64 x 192 slice, once ----
#pragma unroll
  for (int i = 0; i < 12; i++) {
    int u = (tid + i * 256) * 4;          // element index in 64x192
    int r = u / 192, c = u % 192;
    float4 f = *(const float4*)&wt[(size_t)(oBase + r) * 192 + c];
    ushort4 hv;
    hv.x = __builtin_bit_cast(u16, __float2bfloat16(f.x));
    hv.y = __builtin_bit_cast(u16, __float2bfloat16(f.y));
    hv.z = __builtin_bit_cast(u16, __float2bfloat16(f.z));
    hv.w = __builtin_bit_cast(u16, __float2bfloat16(f.w));
    *(ushort4*)&sW[r * SWR + c] = hv;
  }

  // ---- X staging setup ----
  int plane = tid & 63;                   // pos lane within 64
  int cbase = (tid >> 6) * 8;             // 8-c group per wave (wave-uniform)
  const u16* xbase = (const u16*)(in + (size_t)b * C_ * HW_) +
                     (size_t)cbase * HW_ + posBase + plane;

  u16 v[32];
  // chunk 0 loads: 32 scalar u16 (each instr = 64 lanes x 2B contiguous)
#pragma unroll
  for (int cc = 0; cc < 8; cc++)
#pragma unroll
    for (int i = 0; i < 4; i++)
      v[cc * 4 + i] = xbase[(size_t)cc * HW_ + 64 * i];

  f32x4 acc[4][4] = {};

  for (int kc = 0; kc < 6; kc++) {
    // ---- pack & write chunk kc to sX (transposed) ----
#pragma unroll
    for (int i = 0; i < 4; i++) {
      int p = plane + 64 * i;
      ushort4 lo, hi;
      lo.x = v[0 + i];  lo.y = v[4 + i];  lo.z = v[8 + i];  lo.w = v[12 + i];
      hi.x = v[16 + i]; hi.y = v[20 + i]; hi.z = v[24 + i]; hi.w = v[28 + i];
      *(ushort4*)&sX[p * SXR + cbase] = lo;
      *(ushort4*)&sX[p * SXR + cbase + 4] = hi;
    }
    __syncthreads();

    // ---- prefetch next chunk's globals (overlaps MFMA below) ----
    if (kc < 5) {
#pragma unroll
      for (int cc = 0; cc < 8; cc++)
#pragma unroll
        for (int i = 0; i < 4; i++)
          v[cc * 4 + i] = xbase[(size_t)((kc + 1) * 32 + cc) * HW_ + 64 * i];
    }

    // ---- fragments + MFMA ----
    short8 afrag[4];
#pragma unroll
    for (int mt = 0; mt < 4; mt++)
      afrag[mt] = *(const short8*)&sW[(mt * 16 + l15) * SWR + kc * 32 + quad * 8];
#pragma unroll
    for (int nt = 0; nt < 4; nt++) {
      int p = wv * 64 + nt * 16 + l15;
      short4v blo = *(const short4v*)&sX[p * SXR + quad * 8];
      short4v bhi = *(const short4v*)&sX[p * SXR + quad * 8 + 4];
      short8 bfrag;
      bfrag[0] = blo[0]; bfrag[1] = blo[1]; bfrag[2] = blo[2]; bfrag[3] = blo[3];
      bfrag[4] = bhi[0]; bfrag[5] = bhi[1]; bfrag[6] = bhi[2]; bfrag[7] = bhi[3];
#pragma unroll
      for (int mt = 0; mt < 4; mt++)
        acc[mt][nt] = __builtin_amdgcn_mfma_f32_16x16x32_bf16(
            afrag[mt], bfrag, acc[mt][nt], 0, 0, 0);
    }
    __syncthreads();   // all reads done before next chunk's writes
  }

  // ---- epilogue: D row = quad*4 + reg, col = l15 ----
#pragma unroll
  for (int mt = 0; mt < 4; mt++) {
#pragma unroll
    for (int r = 0; r < 4; r++) {
      int o = oBase + mt * 16 + quad * 4 + r;
      float bs = bias[o];
      size_t rowoff = ((size_t)b * C_ + o) * HW_;
#pragma unroll
      for (int nt = 0; nt < 4; nt++) {
        int p = posBase + wv * 64 + nt * 16 + l15;
        float val = acc[mt][nt][r] + bs;
        if (RES) val += ld(residual + rowoff + p);
        st(out + rowoff + p, val);
      }
    }
  }
}

// ---------------------------------------------------------------------------
// Depthwise 3x3, SAME zero padding. w9:[C][9]
// ---------------------------------------------------------------------------
__global__ __launch_bounds__(256) void dw_kernel(
    const bf16* __restrict__ in, const float* __restrict__ w9,
    const float* __restrict__ bias, bf16* __restrict__ out) {
  int idx = blockIdx.x * 256 + threadIdx.x;
  if (idx >= B_ * C_ * HW_) return;
  int pos = idx & (HW_ - 1);
  int bc = idx >> 14;
  int c = bc % C_;
  int h = pos >> 7, w = pos & 127;
  const bf16* ip = in + (size_t)bc * HW_;
  const float* wp = w9 + c * 9;
  float acc = bias[c];
#pragma unroll
  for (int dy = 0; dy < 3; dy++) {
    int hh = h + dy - 1;
    if (hh < 0 || hh >= H_) continue;
#pragma unroll
    for (int dx = 0; dx < 3; dx++) {
      int ww = w + dx - 1;
      if (ww < 0 || ww >= W_) continue;
      acc += ld(ip + hh * W_ + ww) * wp[dy * 3 + dx];
    }
  }
  st(out + idx, acc);
}

// ---------------------------------------------------------------------------
// Gram: logits[b,hd,sk,sq] = sum_pos K[b,hd*S+sk,pos]*Q[b,hd*S+sq,pos]
// ---------------------------------------------------------------------------
__global__ __launch_bounds__(256) void gram_kernel(
    const bf16* __restrict__ Q, const bf16* __restrict__ K,
    float* __restrict__ logits) {
  __shared__ float sK[S_][65];
  __shared__ float sQ[S_][65];
  int bh = blockIdx.y;
  int b = bh >> 2, hd = bh & 3;
  int p0base = blockIdx.x * (HW_ / 16);   // 1024-position chunk
  const bf16* Qb = Q + ((size_t)b * C_ + hd * S_) * HW_;
  const bf16* Kb = K + ((size_t)b * C_ + hd * S_) * HW_;
  int tid = threadIdx.x;
  int tx = tid & 15, ty = tid >> 4;
  float acc[3][3] = {};
  for (int t0 = 0; t0 < 1024; t0 += 64) {
    int p0 = p0base + t0;
#pragma unroll
    for (int i = 0; i < 12; i++) {
      int idx = tid + i * 256;
      int r = idx >> 6, cc = idx & 63;
      sK[r][cc] = ld(Kb + (size_t)r * HW_ + p0 + cc);
      sQ[r][cc] = ld(Qb + (size_t)r * HW_ + p0 + cc);
    }
    __syncthreads();
    for (int p = 0; p < 64; p++) {
      float kv[3], qv[3];
#pragma unroll
      for (int r = 0; r < 3; r++) kv[r] = sK[ty * 3 + r][p];
#pragma unroll
      for (int r = 0; r < 3; r++) qv[r] = sQ[tx * 3 + r][p];
#pragma unroll
      for (int r = 0; r < 3; r++)
#pragma unroll
        for (int q = 0; q < 3; q++) acc[r][q] += kv[r] * qv[q];
    }
    __syncthreads();
  }
  float* lp = logits + (size_t)bh * S_ * S_;
#pragma unroll
  for (int r = 0; r < 3; r++)
#pragma unroll
    for (int q = 0; q < 3; q++)
      atomicAdd(&lp[(ty * 3 + r) * S_ + (tx * 3 + q)], acc[r][q]);
}

// ---------------------------------------------------------------------------
// Softmax over last axis (sq), one thread per (b,hd,sk) row.
// ---------------------------------------------------------------------------
__global__ __launch_bounds__(256) void softmax_kernel(
    const float* __restrict__ logits, const float* __restrict__ alpha,
    float* __restrict__ att) {
  int row = blockIdx.x * 256 + threadIdx.x;   // 0..1535
  if (row >= B_ * HEADS * S_) return;
  float inv_a = 1.0f / alpha[0];
  const float* lp = logits + (size_t)row * S_;
  float v[S_];
  float m = -1e30f;
  for (int i = 0; i < S_; i++) {
    v[i] = lp[i] * inv_a;
    m = fmaxf(m, v[i]);
  }
  float s = 0.f;
  for (int i = 0; i < S_; i++) { v[i] = expf(v[i] - m); s += v[i]; }
  float inv_s = 1.0f / s;
  float* ap = att + (size_t)row * S_;
  for (int i = 0; i < S_; i++) ap[i] = v[i] * inv_s;
}

// ---------------------------------------------------------------------------
// out[b,hd*S+sq,pos] = sum_sk att[b,hd,sk,sq] * V[b,hd*S+sk,pos]
// ---------------------------------------------------------------------------
__global__ __launch_bounds__(256) void av_kernel(
    const bf16* __restrict__ V, const float* __restrict__ att,
    bf16* __restrict__ out) {
  __shared__ float sV[S_][128];
  __shared__ float sA[S_][S_];
  int bh = blockIdx.y;
  int b = bh >> 2, hd = bh & 3;
  int p0 = blockIdx.x * 128;
  const bf16* Vb = V + ((size_t)b * C_ + hd * S_) * HW_;
  int tid = threadIdx.x;
  for (int i = tid; i < S_ * S_; i += 256)
    sA[i / S_][i % S_] = att[(size_t)bh * S_ * S_ + i];
#pragma unroll
  for (int i = 0; i < 24; i++) {
    int idx = tid + i * 256;
    int r = idx >> 7, cc = idx & 127;
    sV[r][cc] = ld(Vb + (size_t)r * HW_ + p0 + cc);
  }
  __syncthreads();
  int px = tid & 127, ty = tid >> 7;   // ty 0..1
  float acc[24];
#pragma unroll
  for (int j = 0; j < 24; j++) acc[j] = 0.f;
  for (int sk = 0; sk < S_; sk++) {
    float v = sV[sk][px];
#pragma unroll
    for (int j = 0; j < 24; j++) acc[j] += v * sA[sk][ty + 2 * j];
  }
  bf16* ob = out + ((size_t)b * C_ + hd * S_) * HW_;
#pragma unroll
  for (int j = 0; j < 24; j++)
    st(ob + (size_t)(ty + 2 * j) * HW_ + p0 + px, acc[j]);
}

// ---------------------------------------------------------------------------
// Spatial 128x128 transpose per (b,c): out[i*W+j] = in[j*W+i]
// ---------------------------------------------------------------------------
__global__ __launch_bounds__(256) void transpose_kernel(
    const bf16* __restrict__ in, bf16* __restrict__ out) {
  __shared__ bf16 tile[32][33];
  int bc = blockIdx.z;
  const bf16* ip = in + (size_t)bc * HW_;
  bf16* op = out + (size_t)bc * HW_;
  int x0 = blockIdx.x * 32, y0 = blockIdx.y * 32;
  int tx = threadIdx.x, ty0 = threadIdx.y;
  for (int i = ty0; i < 32; i += 8)
    tile[i][tx] = ip[(y0 + i) * W_ + x0 + tx];
  __syncthreads();
  for (int i = ty0; i < 32; i += 8)
    op[(x0 + i) * W_ + y0 + tx] = tile[tx][i];
}

// ---------------------------------------------------------------------------
extern "C" void kernel_launch(void* const* d_in, const int* in_sizes, int n_in,
                              void* d_out, int out_size, void* d_ws, size_t ws_size,
                              hipStream_t stream) {
  const float* x      = (const float*)d_in[0];
  const float* ln_w   = (const float*)d_in[1];
  const float* ln_b   = (const float*)d_in[2];
  const float* q_pw_w = (const float*)d_in[3];
  const float* q_pw_b = (const float*)d_in[4];
  const float* q_dw_w = (const float*)d_in[5];
  const float* q_dw_b = (const float*)d_in[6];
  const float* k_pw_w = (const float*)d_in[7];
  const float* k_pw_b = (const float*)d_in[8];
  const float* k_dw_w = (const float*)d_in[9];
  const float* k_dw_b = (const float*)d_in[10];
  const float* v_pw_w = (const float*)d_in[11];
  const float* v_pw_b = (const float*)d_in[12];
  const float* v_dw_w = (const float*)d_in[13];
  const float* v_dw_b = (const float*)d_in[14];
  const float* f_w    = (const float*)d_in[15];
  const float* f_b    = (const float*)d_in[16];
  const float* alpha  = (const float*)d_in[17];
  float* out = (float*)d_out;

  // Workspace (bf16 intermediates): 3*N*2B + 2*73728*4B ~= 152 MB
  size_t N = (size_t)B_ * C_ * HW_;           // 25,165,824
  bf16* xn   = (bf16*)d_ws;                   // LayerNorm output (residual source)
  bf16* tmp  = xn + N;                        // pw outputs / transposed att-out
  bf16* A    = tmp + N;                       // Q, then V
  float* logits = (float*)(A + N);            // [32][48][48]
  float* att    = logits + (size_t)B_ * HEADS * S_ * S_;
  // d_out doubles as scratch: K (bf16) until gram, then att-out (bf16)
  bf16* Kb     = (bf16*)d_out;
  bf16* attout = (bf16*)d_out;

  int nlog = B_ * HEADS * S_ * S_;            // 73728
  zero_kernel<<<dim3(nlog / 256), 256, 0, stream>>>(logits, nlog);

  ln_kernel<<<dim3(B_ * HW_ / 256), 256, 0, stream>>>(x, ln_w, ln_b, xn);

  dim3 gG(HW_ / 256, C_ / 64, B_);            // 64 x 3 x 8 = 1536 blocks
  int dwBlocks = (B_ * C_ * HW_) / 256;

  // Q
  pw_mfma_kernel<false, bf16><<<gG, 256, 0, stream>>>(xn, q_pw_w, q_pw_b, nullptr, tmp);
  dw_kernel<<<dwBlocks, 256, 0, stream>>>(tmp, q_dw_w, q_dw_b, A);
  // K -> d_out scratch
  pw_mfma_kernel<false, bf16><<<gG, 256, 0, stream>>>(xn, k_pw_w, k_pw_b, nullptr, tmp);
  dw_kernel<<<dwBlocks, 256, 0, stream>>>(tmp, k_dw_w, k_dw_b, Kb);
  // attention matrix
  gram_kernel<<<dim3(16, B_ * HEADS), 256, 0, stream>>>(A, Kb, logits);
  softmax_kernel<<<dim3(6), 256, 0, stream>>>(logits, alpha, att);
  // V
  pw_mfma_kernel<false, bf16><<<gG, 256, 0, stream>>>(xn, v_pw_w, v_pw_b, nullptr, tmp);
  dw_kernel<<<dwBlocks, 256, 0, stream>>>(tmp, v_dw_w, v_dw_b, A);
  // att-weighted V -> d_out scratch (K is dead)
  av_kernel<<<dim3(HW_ / 128, B_ * HEADS), 256, 0, stream>>>(A, att, attout);
  // spatial transpose -> tmp
  transpose_kernel<<<dim3(4, 4, B_ * C_), dim3(32, 8), 0, stream>>>(attout, tmp);
  // final projection + bias + residual(xn) -> d_out (fp32)
  pw_mfma_kernel<true, float><<<gG, 256, 0, stream>>>(tmp, f_w, f_b, xn, out);
}

// Round 4
// 612.563 us; speedup vs baseline: 2.7067x; 1.5382x over previous
//
#include <hip/hip_runtime.h>
#include <hip/hip_bf16.h>

#define B_    8
#define C_    192
#define H_    128
#define W_    128
#define HW_   16384
#define HEADS 4
#define S_    48
#define EPS_  1e-5f

typedef __hip_bfloat16 bf16;
typedef unsigned short u16;
typedef __attribute__((ext_vector_type(8))) short short8;
typedef __attribute__((ext_vector_type(4))) short short4v;
typedef __attribute__((ext_vector_type(4))) float f32x4;
typedef __attribute__((ext_vector_type(8))) u16 u16x8;
typedef __attribute__((ext_vector_type(2))) u16 u16x2;

__device__ inline float ld(const bf16* p)  { return __bfloat162float(*p); }
__device__ inline void  st(float* p, float v) { *p = v; }
__device__ inline void  st(bf16* p, float v)  { *p = __float2bfloat16(v); }
__device__ inline float b2f(u16 u) {
  unsigned v = (unsigned)u << 16;
  return __builtin_bit_cast(float, v);
}
__device__ inline u16 f2b(float f) {
  return __builtin_bit_cast(u16, __float2bfloat16(f));
}

// ---------------------------------------------------------------------------
__global__ __launch_bounds__(256) void zero_kernel(float* p, int n) {
  int i = blockIdx.x * 256 + threadIdx.x;
  if (i < n) p[i] = 0.f;
}

// ---------------------------------------------------------------------------
// LayerNorm over channel axis. 2 positions per thread (float2 / ushort2).
// ---------------------------------------------------------------------------
__global__ __launch_bounds__(256) void ln_kernel(
    const float* __restrict__ x, const float* __restrict__ lw,
    const float* __restrict__ lb, bf16* __restrict__ xn) {
  int p2 = blockIdx.x * 256 + threadIdx.x;          // 0 .. B*HW/2
  int b = p2 >> 13;                                 // 8192 pairs per image
  int pos = (p2 & 8191) * 2;
  const float* xp = x + (size_t)b * C_ * HW_ + pos;
  float s0 = 0.f, s1 = 0.f, q0 = 0.f, q1 = 0.f;
  for (int c = 0; c < C_; c++) {
    float2 v = *(const float2*)&xp[(size_t)c * HW_];
    s0 += v.x; s1 += v.y; q0 += v.x * v.x; q1 += v.y * v.y;
  }
  float mu0 = s0 * (1.0f / C_), mu1 = s1 * (1.0f / C_);
  float r0 = rsqrtf(q0 * (1.0f / C_) - mu0 * mu0 + EPS_);
  float r1 = rsqrtf(q1 * (1.0f / C_) - mu1 * mu1 + EPS_);
  u16* op = (u16*)xn + (size_t)b * C_ * HW_ + pos;
  for (int c = 0; c < C_; c++) {
    float2 v = *(const float2*)&xp[(size_t)c * HW_];
    u16x2 o;
    o.x = f2b((v.x - mu0) * r0 * lw[c] + lb[c]);
    o.y = f2b((v.y - mu1) * r1 * lw[c] + lb[c]);
    *(u16x2*)&op[(size_t)c * HW_] = o;
  }
}

// ---------------------------------------------------------------------------
// Pointwise conv via MFMA: out[b,o,p] = sum_c wt[o,c]*in[b,c,p] + bias[o](+res)
// Block: 4 waves, tile 64 o x 256 pos. K=192 in 6 chunks of 32.
// ---------------------------------------------------------------------------
#define SWR 200
#define SXR 36
template <bool RES, typename OutT>
__global__ __launch_bounds__(256) void pw_mfma_kernel(
    const bf16* __restrict__ in, const float* __restrict__ wt,
    const float* __restrict__ bias, const bf16* __restrict__ residual,
    OutT* __restrict__ out) {
  __shared__ __align__(16) u16 sW[64 * SWR];
  __shared__ __align__(16) u16 sX[256 * SXR];
  int tid = threadIdx.x;
  int posBase = blockIdx.x * 256;
  int oBase = blockIdx.y * 64;
  int b = blockIdx.z;
  int wv = tid >> 6, lane = tid & 63;
  int quad = lane >> 4, l15 = lane & 15;

  // ---- stage W (fp32 -> bf16), whole 64 x 192 slice, once ----
#pragma unroll
  for (int i = 0; i < 12; i++) {
    int u = (tid + i * 256) * 4;          // element index in 64x192
    int r = u / 192, c = u % 192;
    float4 f = *(const float4*)&wt[(size_t)(oBase + r) * 192 + c];
    ushort4 hv;
    hv.x = f2b(f.x); hv.y = f2b(f.y); hv.z = f2b(f.z); hv.w = f2b(f.w);
    *(ushort4*)&sW[r * SWR + c] = hv;
  }

  // ---- X staging setup ----
  int plane = tid & 63;                   // pos lane within 64
  int cbase = (tid >> 6) * 8;             // 8-c group per wave (wave-uniform)
  const u16* xbase = (const u16*)(in + (size_t)b * C_ * HW_) +
                     (size_t)cbase * HW_ + posBase + plane;

  u16 v[32];
#pragma unroll
  for (int cc = 0; cc < 8; cc++)
#pragma unroll
    for (int i = 0; i < 4; i++)
      v[cc * 4 + i] = xbase[(size_t)cc * HW_ + 64 * i];

  f32x4 acc[4][4] = {};

  for (int kc = 0; kc < 6; kc++) {
    // ---- pack & write chunk kc to sX (transposed) ----
#pragma unroll
    for (int i = 0; i < 4; i++) {
      int p = plane + 64 * i;
      ushort4 lo, hi;
      lo.x = v[0 + i];  lo.y = v[4 + i];  lo.z = v[8 + i];  lo.w = v[12 + i];
      hi.x = v[16 + i]; hi.y = v[20 + i]; hi.z = v[24 + i]; hi.w = v[28 + i];
      *(ushort4*)&sX[p * SXR + cbase] = lo;
      *(ushort4*)&sX[p * SXR + cbase + 4] = hi;
    }
    __syncthreads();

    // ---- prefetch next chunk's globals (overlaps MFMA below) ----
    if (kc < 5) {
#pragma unroll
      for (int cc = 0; cc < 8; cc++)
#pragma unroll
        for (int i = 0; i < 4; i++)
          v[cc * 4 + i] = xbase[(size_t)((kc + 1) * 32 + cc) * HW_ + 64 * i];
    }

    // ---- fragments + MFMA ----
    short8 afrag[4];
#pragma unroll
    for (int mt = 0; mt < 4; mt++)
      afrag[mt] = *(const short8*)&sW[(mt * 16 + l15) * SWR + kc * 32 + quad * 8];
#pragma unroll
    for (int nt = 0; nt < 4; nt++) {
      int p = wv * 64 + nt * 16 + l15;
      short4v blo = *(const short4v*)&sX[p * SXR + quad * 8];
      short4v bhi = *(const short4v*)&sX[p * SXR + quad * 8 + 4];
      short8 bfrag;
      bfrag[0] = blo[0]; bfrag[1] = blo[1]; bfrag[2] = blo[2]; bfrag[3] = blo[3];
      bfrag[4] = bhi[0]; bfrag[5] = bhi[1]; bfrag[6] = bhi[2]; bfrag[7] = bhi[3];
#pragma unroll
      for (int mt = 0; mt < 4; mt++)
        acc[mt][nt] = __builtin_amdgcn_mfma_f32_16x16x32_bf16(
            afrag[mt], bfrag, acc[mt][nt], 0, 0, 0);
    }
    __syncthreads();
  }

  // ---- epilogue: D row = quad*4 + reg, col = l15 ----
#pragma unroll
  for (int mt = 0; mt < 4; mt++) {
#pragma unroll
    for (int r = 0; r < 4; r++) {
      int o = oBase + mt * 16 + quad * 4 + r;
      float bs = bias[o];
      size_t rowoff = ((size_t)b * C_ + o) * HW_;
#pragma unroll
      for (int nt = 0; nt < 4; nt++) {
        int p = posBase + wv * 64 + nt * 16 + l15;
        float val = acc[mt][nt][r] + bs;
        if (RES) val += ld(residual + rowoff + p);
        st(out + rowoff + p, val);
      }
    }
  }
}

// ---------------------------------------------------------------------------
// Depthwise 3x3, SAME zero pad. LDS-tiled: block = one (b,c), 16 rows x 128.
// Stage 18x128 bf16 via ushort8; each thread computes 8 outputs in a row.
// ---------------------------------------------------------------------------
__global__ __launch_bounds__(256) void dw_kernel(
    const bf16* __restrict__ in, const float* __restrict__ w9,
    const float* __restrict__ bias, bf16* __restrict__ out) {
  __shared__ __align__(16) u16 sT[18 * 128];
  int blk = blockIdx.x;                 // B*C*8
  int bc = blk >> 3;
  int h0 = (blk & 7) * 16;
  int c = bc % C_;
  const u16* ip = (const u16*)in + (size_t)bc * HW_;
  int tid = threadIdx.x;

  // stage rows h0-1 .. h0+16 (zero-fill out-of-range)
  for (int ch = tid; ch < 288; ch += 256) {
    int r = ch >> 4, g = ch & 15;
    int gh = h0 - 1 + r;
    u16x8 val = {};
    if (gh >= 0 && gh < H_) val = *(const u16x8*)&ip[gh * 128 + g * 8];
    *(u16x8*)&sT[r * 128 + g * 8] = val;
  }
  __syncthreads();

  int r_o = tid >> 4, g = tid & 15;
  const float* wp = w9 + c * 9;
  float acc[8];
#pragma unroll
  for (int j = 0; j < 8; j++) acc[j] = bias[c];
#pragma unroll
  for (int k = 0; k < 3; k++) {
    int rr = r_o + k;
    u16x8 mid = *(const u16x8*)&sT[rr * 128 + g * 8];
    float m[8];
#pragma unroll
    for (int j = 0; j < 8; j++) m[j] = b2f(mid[j]);
    float lv = g ? b2f(sT[rr * 128 + g * 8 - 1]) : 0.f;
    float rv = (g < 15) ? b2f(sT[rr * 128 + g * 8 + 8]) : 0.f;
    float wl = wp[k * 3], wc = wp[k * 3 + 1], wr = wp[k * 3 + 2];
#pragma unroll
    for (int j = 0; j < 8; j++) {
      float left  = (j == 0) ? lv : m[j - 1];
      float right = (j == 7) ? rv : m[j + 1];
      acc[j] += wl * left + wc * m[j] + wr * right;
    }
  }
  u16x8 o;
#pragma unroll
  for (int j = 0; j < 8; j++) o[j] = f2b(acc[j]);
  *(u16x8*)((u16*)out + (size_t)bc * HW_ + (h0 + r_o) * 128 + g * 8) = o;
}

// ---------------------------------------------------------------------------
// Gram: logits[b,hd,sk,sq] = sum_pos K[b,hd*S+sk,pos]*Q[b,hd*S+sq,pos]
// ---------------------------------------------------------------------------
__global__ __launch_bounds__(256) void gram_kernel(
    const bf16* __restrict__ Q, const bf16* __restrict__ K,
    float* __restrict__ logits) {
  __shared__ float sK[S_][65];
  __shared__ float sQ[S_][65];
  int bh = blockIdx.y;
  int b = bh >> 2, hd = bh & 3;
  int p0base = blockIdx.x * (HW_ / 16);   // 1024-position chunk
  const bf16* Qb = Q + ((size_t)b * C_ + hd * S_) * HW_;
  const bf16* Kb = K + ((size_t)b * C_ + hd * S_) * HW_;
  int tid = threadIdx.x;
  int tx = tid & 15, ty = tid >> 4;
  float acc[3][3] = {};
  for (int t0 = 0; t0 < 1024; t0 += 64) {
    int p0 = p0base + t0;
#pragma unroll
    for (int i = 0; i < 12; i++) {
      int idx = tid + i * 256;
      int r = idx >> 6, cc = idx & 63;
      sK[r][cc] = ld(Kb + (size_t)r * HW_ + p0 + cc);
      sQ[r][cc] = ld(Qb + (size_t)r * HW_ + p0 + cc);
    }
    __syncthreads();
    for (int p = 0; p < 64; p++) {
      float kv[3], qv[3];
#pragma unroll
      for (int r = 0; r < 3; r++) kv[r] = sK[ty * 3 + r][p];
#pragma unroll
      for (int r = 0; r < 3; r++) qv[r] = sQ[tx * 3 + r][p];
#pragma unroll
      for (int r = 0; r < 3; r++)
#pragma unroll
        for (int q = 0; q < 3; q++) acc[r][q] += kv[r] * qv[q];
    }
    __syncthreads();
  }
  float* lp = logits + (size_t)bh * S_ * S_;
#pragma unroll
  for (int r = 0; r < 3; r++)
#pragma unroll
    for (int q = 0; q < 3; q++)
      atomicAdd(&lp[(ty * 3 + r) * S_ + (tx * 3 + q)], acc[r][q]);
}

// ---------------------------------------------------------------------------
// Softmax over last axis (sq), one thread per (b,hd,sk) row.
// ---------------------------------------------------------------------------
__global__ __launch_bounds__(256) void softmax_kernel(
    const float* __restrict__ logits, const float* __restrict__ alpha,
    float* __restrict__ att) {
  int row = blockIdx.x * 256 + threadIdx.x;   // 0..1535
  if (row >= B_ * HEADS * S_) return;
  float inv_a = 1.0f / alpha[0];
  const float* lp = logits + (size_t)row * S_;
  float v[S_];
  float m = -1e30f;
  for (int i = 0; i < S_; i++) {
    v[i] = lp[i] * inv_a;
    m = fmaxf(m, v[i]);
  }
  float s = 0.f;
  for (int i = 0; i < S_; i++) { v[i] = expf(v[i] - m); s += v[i]; }
  float inv_s = 1.0f / s;
  float* ap = att + (size_t)row * S_;
  for (int i = 0; i < S_; i++) ap[i] = v[i] * inv_s;
}

// ---------------------------------------------------------------------------
// out[b,hd*S+sq,pos] = sum_sk att[b,hd,sk,sq] * V[b,hd*S+sk,pos]
// ---------------------------------------------------------------------------
__global__ __launch_bounds__(256) void av_kernel(
    const bf16* __restrict__ V, const float* __restrict__ att,
    bf16* __restrict__ out) {
  __shared__ float sV[S_][128];
  __shared__ float sA[S_][S_];
  int bh = blockIdx.y;
  int b = bh >> 2, hd = bh & 3;
  int p0 = blockIdx.x * 128;
  const bf16* Vb = V + ((size_t)b * C_ + hd * S_) * HW_;
  int tid = threadIdx.x;
  for (int i = tid; i < S_ * S_; i += 256)
    sA[i / S_][i % S_] = att[(size_t)bh * S_ * S_ + i];
#pragma unroll
  for (int i = 0; i < 24; i++) {
    int idx = tid + i * 256;
    int r = idx >> 7, cc = idx & 127;
    sV[r][cc] = ld(Vb + (size_t)r * HW_ + p0 + cc);
  }
  __syncthreads();
  int px = tid & 127, ty = tid >> 7;   // ty 0..1
  float acc[24];
#pragma unroll
  for (int j = 0; j < 24; j++) acc[j] = 0.f;
  for (int sk = 0; sk < S_; sk++) {
    float v = sV[sk][px];
#pragma unroll
    for (int j = 0; j < 24; j++) acc[j] += v * sA[sk][ty + 2 * j];
  }
  bf16* ob = out + ((size_t)b * C_ + hd * S_) * HW_;
#pragma unroll
  for (int j = 0; j < 24; j++)
    st(ob + (size_t)(ty + 2 * j) * HW_ + p0 + px, acc[j]);
}

// ---------------------------------------------------------------------------
// Spatial 128x128 transpose per (b,c): out[i*W+j] = in[j*W+i]
// ---------------------------------------------------------------------------
__global__ __launch_bounds__(256) void transpose_kernel(
    const bf16* __restrict__ in, bf16* __restrict__ out) {
  __shared__ bf16 tile[32][33];
  int bc = blockIdx.z;
  const bf16* ip = in + (size_t)bc * HW_;
  bf16* op = out + (size_t)bc * HW_;
  int x0 = blockIdx.x * 32, y0 = blockIdx.y * 32;
  int tx = threadIdx.x, ty0 = threadIdx.y;
  for (int i = ty0; i < 32; i += 8)
    tile[i][tx] = ip[(y0 + i) * W_ + x0 + tx];
  __syncthreads();
  for (int i = ty0; i < 32; i += 8)
    op[(x0 + i) * W_ + y0 + tx] = tile[tx][i];
}

// ---------------------------------------------------------------------------
extern "C" void kernel_launch(void* const* d_in, const int* in_sizes, int n_in,
                              void* d_out, int out_size, void* d_ws, size_t ws_size,
                              hipStream_t stream) {
  const float* x      = (const float*)d_in[0];
  const float* ln_w   = (const float*)d_in[1];
  const float* ln_b   = (const float*)d_in[2];
  const float* q_pw_w = (const float*)d_in[3];
  const float* q_pw_b = (const float*)d_in[4];
  const float* q_dw_w = (const float*)d_in[5];
  const float* q_dw_b = (const float*)d_in[6];
  const float* k_pw_w = (const float*)d_in[7];
  const float* k_pw_b = (const float*)d_in[8];
  const float* k_dw_w = (const float*)d_in[9];
  const float* k_dw_b = (const float*)d_in[10];
  const float* v_pw_w = (const float*)d_in[11];
  const float* v_pw_b = (const float*)d_in[12];
  const float* v_dw_w = (const float*)d_in[13];
  const float* v_dw_b = (const float*)d_in[14];
  const float* f_w    = (const float*)d_in[15];
  const float* f_b    = (const float*)d_in[16];
  const float* alpha  = (const float*)d_in[17];
  float* out = (float*)d_out;

  size_t N = (size_t)B_ * C_ * HW_;           // 25,165,824
  bf16* xn   = (bf16*)d_ws;                   // LayerNorm output (residual source)
  bf16* tmp  = xn + N;                        // pw outputs / transposed att-out
  bf16* A    = tmp + N;                       // Q, then V
  float* logits = (float*)(A + N);            // [32][48][48]
  float* att    = logits + (size_t)B_ * HEADS * S_ * S_;
  bf16* Kb     = (bf16*)d_out;                // d_out as scratch
  bf16* attout = (bf16*)d_out;

  int nlog = B_ * HEADS * S_ * S_;            // 73728
  zero_kernel<<<dim3(nlog / 256), 256, 0, stream>>>(logits, nlog);

  ln_kernel<<<dim3(B_ * HW_ / 512), 256, 0, stream>>>(x, ln_w, ln_b, xn);

  dim3 gG(HW_ / 256, C_ / 64, B_);            // 64 x 3 x 8 = 1536 blocks
  int dwBlocks = B_ * C_ * 8;                 // 12288

  // Q
  pw_mfma_kernel<false, bf16><<<gG, 256, 0, stream>>>(xn, q_pw_w, q_pw_b, nullptr, tmp);
  dw_kernel<<<dwBlocks, 256, 0, stream>>>(tmp, q_dw_w, q_dw_b, A);
  // K -> d_out scratch
  pw_mfma_kernel<false, bf16><<<gG, 256, 0, stream>>>(xn, k_pw_w, k_pw_b, nullptr, tmp);
  dw_kernel<<<dwBlocks, 256, 0, stream>>>(tmp, k_dw_w, k_dw_b, Kb);
  // attention matrix
  gram_kernel<<<dim3(16, B_ * HEADS), 256, 0, stream>>>(A, Kb, logits);
  softmax_kernel<<<dim3(6), 256, 0, stream>>>(logits, alpha, att);
  // V
  pw_mfma_kernel<false, bf16><<<gG, 256, 0, stream>>>(xn, v_pw_w, v_pw_b, nullptr, tmp);
  dw_kernel<<<dwBlocks, 256, 0, stream>>>(tmp, v_dw_w, v_dw_b, A);
  // att-weighted V -> d_out scratch (K is dead)
  av_kernel<<<dim3(HW_ / 128, B_ * HEADS), 256, 0, stream>>>(A, att, attout);
  // spatial transpose -> tmp
  transpose_kernel<<<dim3(4, 4, B_ * C_), dim3(32, 8), 0, stream>>>(attout, tmp);
  // final projection + bias + residual(xn) -> d_out (fp32)
  pw_mfma_kernel<true, float><<<gG, 256, 0, stream>>>(tmp, f_w, f_b, xn, out);
}

// Round 5
// 553.259 us; speedup vs baseline: 2.9968x; 1.1072x over previous
//
#include <hip/hip_runtime.h>
#include <hip/hip_bf16.h>

#define B_    8
#define C_    192
#define H_    128
#define W_    128
#define HW_   16384
#define HEADS 4
#define S_    48
#define EPS_  1e-5f

typedef __hip_bfloat16 bf16;
typedef unsigned short u16;
typedef __attribute__((ext_vector_type(8))) short short8;
typedef __attribute__((ext_vector_type(4))) short short4v;
typedef __attribute__((ext_vector_type(4))) float f32x4;
typedef __attribute__((ext_vector_type(8))) u16 u16x8;
typedef __attribute__((ext_vector_type(4))) u16 u16x4;
typedef __attribute__((ext_vector_type(2))) u16 u16x2;

__device__ inline float ld(const bf16* p)  { return __bfloat162float(*p); }
__device__ inline void  st(float* p, float v) { *p = v; }
__device__ inline void  st(bf16* p, float v)  { *p = __float2bfloat16(v); }
__device__ inline float b2f(u16 u) {
  unsigned v = (unsigned)u << 16;
  return __builtin_bit_cast(float, v);
}
__device__ inline u16 f2b(float f) {
  return __builtin_bit_cast(u16, __float2bfloat16(f));
}

// ---------------------------------------------------------------------------
__global__ __launch_bounds__(256) void zero_kernel(float* p, int n) {
  int i = blockIdx.x * 256 + threadIdx.x;
  if (i < n) p[i] = 0.f;
}

// ---------------------------------------------------------------------------
// LayerNorm over channel axis. 4 positions per thread (float4 / ushort4).
// ---------------------------------------------------------------------------
__global__ __launch_bounds__(256) void ln_kernel(
    const float* __restrict__ x, const float* __restrict__ lw,
    const float* __restrict__ lb, bf16* __restrict__ xn) {
  int p4 = blockIdx.x * 256 + threadIdx.x;          // 0 .. B*HW/4
  int b = p4 >> 12;                                 // 4096 quads per image
  int pos = (p4 & 4095) * 4;
  const float* xp = x + (size_t)b * C_ * HW_ + pos;
  float s[4] = {}, q[4] = {};
  for (int c = 0; c < C_; c++) {
    float4 v = *(const float4*)&xp[(size_t)c * HW_];
    s[0] += v.x; s[1] += v.y; s[2] += v.z; s[3] += v.w;
    q[0] += v.x * v.x; q[1] += v.y * v.y; q[2] += v.z * v.z; q[3] += v.w * v.w;
  }
  float mu[4], r[4];
#pragma unroll
  for (int i = 0; i < 4; i++) {
    mu[i] = s[i] * (1.0f / C_);
    r[i] = rsqrtf(q[i] * (1.0f / C_) - mu[i] * mu[i] + EPS_);
  }
  u16* op = (u16*)xn + (size_t)b * C_ * HW_ + pos;
  for (int c = 0; c < C_; c++) {
    float4 v = *(const float4*)&xp[(size_t)c * HW_];
    float wv = lw[c], bv = lb[c];
    u16x4 o;
    o.x = f2b((v.x - mu[0]) * r[0] * wv + bv);
    o.y = f2b((v.y - mu[1]) * r[1] * wv + bv);
    o.z = f2b((v.z - mu[2]) * r[2] * wv + bv);
    o.w = f2b((v.w - mu[3]) * r[3] * wv + bv);
    *(u16x4*)&op[(size_t)c * HW_] = o;
  }
}

// ---------------------------------------------------------------------------
// Pointwise conv via MFMA: out[b,o,p] = sum_c wt[o,c]*in[b,c,p] + bias[o](+res)
// Block: 4 waves, tile 64 o x 256 pos. K=192 in 6 chunks of 32.
// ---------------------------------------------------------------------------
#define SWR 200
#define SXR 36
template <bool RES, typename OutT>
__global__ __launch_bounds__(256) void pw_mfma_kernel(
    const bf16* __restrict__ in, const float* __restrict__ wt,
    const float* __restrict__ bias, const bf16* __restrict__ residual,
    OutT* __restrict__ out) {
  __shared__ __align__(16) u16 sW[64 * SWR];
  __shared__ __align__(16) u16 sX[256 * SXR];
  int tid = threadIdx.x;
  int posBase = blockIdx.x * 256;
  int oBase = blockIdx.y * 64;
  int b = blockIdx.z;
  int wv = tid >> 6, lane = tid & 63;
  int quad = lane >> 4, l15 = lane & 15;

  // ---- stage W (fp32 -> bf16), whole 64 x 192 slice, once ----
#pragma unroll
  for (int i = 0; i < 12; i++) {
    int u = (tid + i * 256) * 4;          // element index in 64x192
    int r = u / 192, c = u % 192;
    float4 f = *(const float4*)&wt[(size_t)(oBase + r) * 192 + c];
    ushort4 hv;
    hv.x = f2b(f.x); hv.y = f2b(f.y); hv.z = f2b(f.z); hv.w = f2b(f.w);
    *(ushort4*)&sW[r * SWR + c] = hv;
  }

  // ---- X staging setup ----
  int plane = tid & 63;                   // pos lane within 64
  int cbase = (tid >> 6) * 8;             // 8-c group per wave (wave-uniform)
  const u16* xbase = (const u16*)(in + (size_t)b * C_ * HW_) +
                     (size_t)cbase * HW_ + posBase + plane;

  u16 v[32];
#pragma unroll
  for (int cc = 0; cc < 8; cc++)
#pragma unroll
    for (int i = 0; i < 4; i++)
      v[cc * 4 + i] = xbase[(size_t)cc * HW_ + 64 * i];

  f32x4 acc[4][4] = {};

  for (int kc = 0; kc < 6; kc++) {
    // ---- pack & write chunk kc to sX (transposed) ----
#pragma unroll
    for (int i = 0; i < 4; i++) {
      int p = plane + 64 * i;
      ushort4 lo, hi;
      lo.x = v[0 + i];  lo.y = v[4 + i];  lo.z = v[8 + i];  lo.w = v[12 + i];
      hi.x = v[16 + i]; hi.y = v[20 + i]; hi.z = v[24 + i]; hi.w = v[28 + i];
      *(ushort4*)&sX[p * SXR + cbase] = lo;
      *(ushort4*)&sX[p * SXR + cbase + 4] = hi;
    }
    __syncthreads();

    // ---- prefetch next chunk's globals (overlaps MFMA below) ----
    if (kc < 5) {
#pragma unroll
      for (int cc = 0; cc < 8; cc++)
#pragma unroll
        for (int i = 0; i < 4; i++)
          v[cc * 4 + i] = xbase[(size_t)((kc + 1) * 32 + cc) * HW_ + 64 * i];
    }

    // ---- fragments + MFMA ----
    short8 afrag[4];
#pragma unroll
    for (int mt = 0; mt < 4; mt++)
      afrag[mt] = *(const short8*)&sW[(mt * 16 + l15) * SWR + kc * 32 + quad * 8];
#pragma unroll
    for (int nt = 0; nt < 4; nt++) {
      int p = wv * 64 + nt * 16 + l15;
      short4v blo = *(const short4v*)&sX[p * SXR + quad * 8];
      short4v bhi = *(const short4v*)&sX[p * SXR + quad * 8 + 4];
      short8 bfrag;
      bfrag[0] = blo[0]; bfrag[1] = blo[1]; bfrag[2] = blo[2]; bfrag[3] = blo[3];
      bfrag[4] = bhi[0]; bfrag[5] = bhi[1]; bfrag[6] = bhi[2]; bfrag[7] = bhi[3];
#pragma unroll
      for (int mt = 0; mt < 4; mt++)
        acc[mt][nt] = __builtin_amdgcn_mfma_f32_16x16x32_bf16(
            afrag[mt], bfrag, acc[mt][nt], 0, 0, 0);
    }
    __syncthreads();
  }

  // ---- epilogue: D row = quad*4 + reg, col = l15 ----
#pragma unroll
  for (int mt = 0; mt < 4; mt++) {
#pragma unroll
    for (int r = 0; r < 4; r++) {
      int o = oBase + mt * 16 + quad * 4 + r;
      float bs = bias[o];
      size_t rowoff = ((size_t)b * C_ + o) * HW_;
#pragma unroll
      for (int nt = 0; nt < 4; nt++) {
        int p = posBase + wv * 64 + nt * 16 + l15;
        float val = acc[mt][nt][r] + bs;
        if (RES) val += ld(residual + rowoff + p);
        st(out + rowoff + p, val);
      }
    }
  }
}

// ---------------------------------------------------------------------------
// Depthwise 3x3, SAME zero pad. LDS-tiled: block = one (b,c), 16 rows x 128.
// ---------------------------------------------------------------------------
__global__ __launch_bounds__(256) void dw_kernel(
    const bf16* __restrict__ in, const float* __restrict__ w9,
    const float* __restrict__ bias, bf16* __restrict__ out) {
  __shared__ __align__(16) u16 sT[18 * 128];
  int blk = blockIdx.x;                 // B*C*8
  int bc = blk >> 3;
  int h0 = (blk & 7) * 16;
  int c = bc % C_;
  const u16* ip = (const u16*)in + (size_t)bc * HW_;
  int tid = threadIdx.x;

  for (int ch = tid; ch < 288; ch += 256) {
    int r = ch >> 4, g = ch & 15;
    int gh = h0 - 1 + r;
    u16x8 val = {};
    if (gh >= 0 && gh < H_) val = *(const u16x8*)&ip[gh * 128 + g * 8];
    *(u16x8*)&sT[r * 128 + g * 8] = val;
  }
  __syncthreads();

  int r_o = tid >> 4, g = tid & 15;
  const float* wp = w9 + c * 9;
  float acc[8];
#pragma unroll
  for (int j = 0; j < 8; j++) acc[j] = bias[c];
#pragma unroll
  for (int k = 0; k < 3; k++) {
    int rr = r_o + k;
    u16x8 mid = *(const u16x8*)&sT[rr * 128 + g * 8];
    float m[8];
#pragma unroll
    for (int j = 0; j < 8; j++) m[j] = b2f(mid[j]);
    float lv = g ? b2f(sT[rr * 128 + g * 8 - 1]) : 0.f;
    float rv = (g < 15) ? b2f(sT[rr * 128 + g * 8 + 8]) : 0.f;
    float wl = wp[k * 3], wc = wp[k * 3 + 1], wr = wp[k * 3 + 2];
#pragma unroll
    for (int j = 0; j < 8; j++) {
      float left  = (j == 0) ? lv : m[j - 1];
      float right = (j == 7) ? rv : m[j + 1];
      acc[j] += wl * left + wc * m[j] + wr * right;
    }
  }
  u16x8 o;
#pragma unroll
  for (int j = 0; j < 8; j++) o[j] = f2b(acc[j]);
  *(u16x8*)((u16*)out + (size_t)bc * HW_ + (h0 + r_o) * 128 + g * 8) = o;
}

// ---------------------------------------------------------------------------
// Gram via MFMA, no LDS staging: pos is the K-dim and is contiguous for both
// operands -> direct global short8 fragment loads.
// logits[bh][sk][sq] = sum_pos K[sk,pos]*Q[sq,pos]
// Grid: (16 pos-chunks, 32 bh). Each wave: full 48x48, 256 positions.
// 4-wave LDS reduce, then one atomicAdd per element per block.
// ---------------------------------------------------------------------------
__global__ __launch_bounds__(256) void gram_mfma_kernel(
    const bf16* __restrict__ Q, const bf16* __restrict__ K,
    float* __restrict__ logits) {
  __shared__ float sP[4][S_ * S_];
  int bh = blockIdx.y;
  int b = bh >> 2, hd = bh & 3;
  int tid = threadIdx.x;
  int wv = tid >> 6, lane = tid & 63;
  int quad = lane >> 4, l15 = lane & 15;
  const u16* Qb = (const u16*)Q + ((size_t)b * C_ + hd * S_) * HW_;
  const u16* Kb = (const u16*)K + ((size_t)b * C_ + hd * S_) * HW_;
  int pbase = blockIdx.x * 1024 + wv * 256 + quad * 8;

  f32x4 acc[3][3] = {};
#pragma unroll
  for (int t = 0; t < 8; t++) {
    int p = pbase + t * 32;
    short8 a[3], bb[3];
#pragma unroll
    for (int mi = 0; mi < 3; mi++)
      a[mi] = *(const short8*)&Kb[(size_t)(mi * 16 + l15) * HW_ + p];
#pragma unroll
    for (int ni = 0; ni < 3; ni++)
      bb[ni] = *(const short8*)&Qb[(size_t)(ni * 16 + l15) * HW_ + p];
#pragma unroll
    for (int mi = 0; mi < 3; mi++)
#pragma unroll
      for (int ni = 0; ni < 3; ni++)
        acc[mi][ni] = __builtin_amdgcn_mfma_f32_16x16x32_bf16(
            a[mi], bb[ni], acc[mi][ni], 0, 0, 0);
  }

  // write partials: D row(sk) = quad*4+reg, col(sq) = l15
#pragma unroll
  for (int mi = 0; mi < 3; mi++)
#pragma unroll
    for (int r = 0; r < 4; r++) {
      int sk = mi * 16 + quad * 4 + r;
#pragma unroll
      for (int ni = 0; ni < 3; ni++)
        sP[wv][sk * S_ + ni * 16 + l15] = acc[mi][ni][r];
    }
  __syncthreads();

  float* lp = logits + (size_t)bh * S_ * S_;
  for (int e = tid; e < S_ * S_; e += 256)
    atomicAdd(&lp[e], sP[0][e] + sP[1][e] + sP[2][e] + sP[3][e]);
}

// ---------------------------------------------------------------------------
// Softmax over last axis (sq), one thread per (b,hd,sk) row.
// ---------------------------------------------------------------------------
__global__ __launch_bounds__(256) void softmax_kernel(
    const float* __restrict__ logits, const float* __restrict__ alpha,
    float* __restrict__ att) {
  int row = blockIdx.x * 256 + threadIdx.x;   // 0..1535
  if (row >= B_ * HEADS * S_) return;
  float inv_a = 1.0f / alpha[0];
  const float* lp = logits + (size_t)row * S_;
  float v[S_];
  float m = -1e30f;
  for (int i = 0; i < S_; i++) {
    v[i] = lp[i] * inv_a;
    m = fmaxf(m, v[i]);
  }
  float s = 0.f;
  for (int i = 0; i < S_; i++) { v[i] = expf(v[i] - m); s += v[i]; }
  float inv_s = 1.0f / s;
  float* ap = att + (size_t)row * S_;
  for (int i = 0; i < S_; i++) ap[i] = v[i] * inv_s;
}

// ---------------------------------------------------------------------------
// out[b,hd*S+sq,pos] = sum_sk att[b,hd,sk,sq] * V[b,hd*S+sk,pos]
// ---------------------------------------------------------------------------
__global__ __launch_bounds__(256) void av_kernel(
    const bf16* __restrict__ V, const float* __restrict__ att,
    bf16* __restrict__ out) {
  __shared__ float sV[S_][128];
  __shared__ float sA[S_][S_];
  int bh = blockIdx.y;
  int b = bh >> 2, hd = bh & 3;
  int p0 = blockIdx.x * 128;
  const u16* Vb = (const u16*)V + ((size_t)b * C_ + hd * S_) * HW_;
  int tid = threadIdx.x;
  for (int i = tid; i < S_ * S_; i += 256)
    sA[i / S_][i % S_] = att[(size_t)bh * S_ * S_ + i];
#pragma unroll
  for (int i = 0; i < 3; i++) {
    int e = tid + i * 256;               // 0..767 over 48 rows x 16 groups
    int r = e >> 4, g = e & 15;
    u16x8 v8 = *(const u16x8*)&Vb[(size_t)r * HW_ + p0 + g * 8];
#pragma unroll
    for (int j = 0; j < 8; j++) sV[r][g * 8 + j] = b2f(v8[j]);
  }
  __syncthreads();
  int px = tid & 127, ty = tid >> 7;   // ty 0..1
  float acc[24];
#pragma unroll
  for (int j = 0; j < 24; j++) acc[j] = 0.f;
  for (int sk = 0; sk < S_; sk++) {
    float v = sV[sk][px];
#pragma unroll
    for (int j = 0; j < 24; j++) acc[j] += v * sA[sk][ty + 2 * j];
  }
  bf16* ob = out + ((size_t)b * C_ + hd * S_) * HW_;
#pragma unroll
  for (int j = 0; j < 24; j++)
    st(ob + (size_t)(ty + 2 * j) * HW_ + p0 + px, acc[j]);
}

// ---------------------------------------------------------------------------
// Spatial 128x128 transpose per (b,c): out[i*W+j] = in[j*W+i]
// ---------------------------------------------------------------------------
__global__ __launch_bounds__(256) void transpose_kernel(
    const bf16* __restrict__ in, bf16* __restrict__ out) {
  __shared__ bf16 tile[32][33];
  int bc = blockIdx.z;
  const bf16* ip = in + (size_t)bc * HW_;
  bf16* op = out + (size_t)bc * HW_;
  int x0 = blockIdx.x * 32, y0 = blockIdx.y * 32;
  int tx = threadIdx.x, ty0 = threadIdx.y;
  for (int i = ty0; i < 32; i += 8)
    tile[i][tx] = ip[(y0 + i) * W_ + x0 + tx];
  __syncthreads();
  for (int i = ty0; i < 32; i += 8)
    op[(x0 + i) * W_ + y0 + tx] = tile[tx][i];
}

// ---------------------------------------------------------------------------
extern "C" void kernel_launch(void* const* d_in, const int* in_sizes, int n_in,
                              void* d_out, int out_size, void* d_ws, size_t ws_size,
                              hipStream_t stream) {
  const float* x      = (const float*)d_in[0];
  const float* ln_w   = (const float*)d_in[1];
  const float* ln_b   = (const float*)d_in[2];
  const float* q_pw_w = (const float*)d_in[3];
  const float* q_pw_b = (const float*)d_in[4];
  const float* q_dw_w = (const float*)d_in[5];
  const float* q_dw_b = (const float*)d_in[6];
  const float* k_pw_w = (const float*)d_in[7];
  const float* k_pw_b = (const float*)d_in[8];
  const float* k_dw_w = (const float*)d_in[9];
  const float* k_dw_b = (const float*)d_in[10];
  const float* v_pw_w = (const float*)d_in[11];
  const float* v_pw_b = (const float*)d_in[12];
  const float* v_dw_w = (const float*)d_in[13];
  const float* v_dw_b = (const float*)d_in[14];
  const float* f_w    = (const float*)d_in[15];
  const float* f_b    = (const float*)d_in[16];
  const float* alpha  = (const float*)d_in[17];
  float* out = (float*)d_out;

  size_t N = (size_t)B_ * C_ * HW_;           // 25,165,824
  bf16* xn   = (bf16*)d_ws;                   // LayerNorm output (residual source)
  bf16* tmp  = xn + N;                        // pw outputs / transposed att-out
  bf16* A    = tmp + N;                       // Q, then V
  float* logits = (float*)(A + N);            // [32][48][48]
  float* att    = logits + (size_t)B_ * HEADS * S_ * S_;
  bf16* Kb     = (bf16*)d_out;                // d_out as scratch
  bf16* attout = (bf16*)d_out;

  int nlog = B_ * HEADS * S_ * S_;            // 73728
  zero_kernel<<<dim3(nlog / 256), 256, 0, stream>>>(logits, nlog);

  ln_kernel<<<dim3(B_ * HW_ / 1024), 256, 0, stream>>>(x, ln_w, ln_b, xn);

  dim3 gG(HW_ / 256, C_ / 64, B_);            // 64 x 3 x 8 = 1536 blocks
  int dwBlocks = B_ * C_ * 8;                 // 12288

  // Q
  pw_mfma_kernel<false, bf16><<<gG, 256, 0, stream>>>(xn, q_pw_w, q_pw_b, nullptr, tmp);
  dw_kernel<<<dwBlocks, 256, 0, stream>>>(tmp, q_dw_w, q_dw_b, A);
  // K -> d_out scratch
  pw_mfma_kernel<false, bf16><<<gG, 256, 0, stream>>>(xn, k_pw_w, k_pw_b, nullptr, tmp);
  dw_kernel<<<dwBlocks, 256, 0, stream>>>(tmp, k_dw_w, k_dw_b, Kb);
  // attention matrix (A operand = K, B operand = Q)
  gram_mfma_kernel<<<dim3(16, B_ * HEADS), 256, 0, stream>>>(A, Kb, logits);
  softmax_kernel<<<dim3(6), 256, 0, stream>>>(logits, alpha, att);
  // V
  pw_mfma_kernel<false, bf16><<<gG, 256, 0, stream>>>(xn, v_pw_w, v_pw_b, nullptr, tmp);
  dw_kernel<<<dwBlocks, 256, 0, stream>>>(tmp, v_dw_w, v_dw_b, A);
  // att-weighted V -> d_out scratch (K is dead)
  av_kernel<<<dim3(HW_ / 128, B_ * HEADS), 256, 0, stream>>>(A, att, attout);
  // spatial transpose -> tmp
  transpose_kernel<<<dim3(4, 4, B_ * C_), dim3(32, 8), 0, stream>>>(attout, tmp);
  // final projection + bias + residual(xn) -> d_out (fp32)
  pw_mfma_kernel<true, float><<<gG, 256, 0, stream>>>(tmp, f_w, f_b, xn, out);
}